// Round 8
// baseline (122.203 us; speedup 1.0000x reference)
//
#include <hip/hip_runtime.h>
#include <stdint.h>

#define NPIX 3136      // 56*56
#define OC 256
#define IC 256
#define CPF 32
#define BUF_FLOATS 3456  // 13 DMA chunks * 256 + pad + zero row
#define ZROW 3360        // zero "row" (64 floats zeroed; serves halo rows)

typedef const __attribute__((address_space(1))) uint32_t* gptr_t;
typedef __attribute__((address_space(3))) uint32_t* lptr_t;

// lane s gets lane s-1's value within 16-lane DPP row; s%16==0 -> 0
__device__ __forceinline__ float dpp_shr1(float v) {
    return __int_as_float(__builtin_amdgcn_update_dpp(
        0, __float_as_int(v), 0x111, 0xF, 0xF, true));
}
// lane s gets lane s+1's value within 16-lane DPP row; s%16==15 -> 0
__device__ __forceinline__ float dpp_shl1(float v) {
    return __int_as_float(__builtin_amdgcn_update_dpp(
        0, __float_as_int(v), 0x101, 0xF, 0xF, true));
}

// One block per (b,o). Plane staged via global_load_lds DMA, double-buffered,
// manually 2-phase unrolled so buffer bases are compile-time. Thread
// (g = t>>4, s = t&15) computes a 4x4 output tile; row addresses hoisted out
// of the channel loop; weights/connections staged once into LDS.
__global__ __launch_bounds__(256, 4) void sparse_conv_kernel(
    const float* __restrict__ x, const float* __restrict__ weight,
    const int* __restrict__ connections, float* __restrict__ out)
{
    __shared__ __align__(16) float buf[2][BUF_FLOATS];
    __shared__ __align__(16) float wlds[CPF * 12];   // 9 weights padded to 12
    __shared__ int clds[CPF];

    const int bid = blockIdx.x;
    const int b = bid & 3;        // each XCD sees exactly one batch's x (L2-fit)
    const int o = bid >> 2;
    const int t = threadIdx.x;
    const int lane = t & 63;
    const int wv = t >> 6;

    if (t < 64) { buf[0][ZROW + t] = 0.f; buf[1][ZROW + t] = 0.f; }

    // Stage weights (strided 9 -> 12 for float4 reads) and connections once.
    {
        const float* wo = weight + o * CPF * 9;
        for (int i = t; i < CPF * 9; i += 256) {
            int c = i / 9, k = i - c * 9;
            wlds[c * 12 + k] = wo[i];
        }
        if (t < CPF) clds[t] = connections[o * CPF + t];
    }

    // DMA chunk offsets, hoisted: wave0 -> chunks 0..3, wave w -> 3w+1..3w+3.
    const int cbase = (wv == 0) ? 0 : (3 * wv + 1);
    const int cnum  = (wv == 0) ? 4 : 3;
    int goffs[4], coffs[4];
#pragma unroll
    for (int i = 0; i < 4; ++i) {
        const int chunk = cbase + i;
        int go = chunk * 256 + lane * 4;
        goffs[i] = (go > 3132) ? 3132 : go;   // tail clamp (garbage lands < ZROW)
        coffs[i] = chunk * 256;
    }

    const float* xb = x + (size_t)b * IC * NPIX;
    const int s = t & 15;
    const int g = t >> 4;
    const bool active = (g < 14);

    // Hoisted per-thread LDS row offsets (float indices), reused for all 32 ch.
    int ro[6];
#pragma unroll
    for (int k = 0; k < 6; ++k) {
        const int rr = 4 * g - 1 + k;
        ro[k] = (((unsigned)rr < 56u) ? rr * 56 : ZROW) + 4 * s;
    }

    float4 acc[4];
#pragma unroll
    for (int r = 0; r < 4; ++r) acc[r] = make_float4(0.f, 0.f, 0.f, 0.f);

    __syncthreads();   // wlds/clds/zero-row visible

    auto dma = [&](int c, float* dst) {
        const float* plane = xb + (size_t)clds[c] * NPIX;
        for (int i = 0; i < cnum; ++i)
            __builtin_amdgcn_global_load_lds((gptr_t)(plane + goffs[i]),
                                             (lptr_t)(dst + coffs[i]), 16, 0, 0);
    };

    auto compute = [&](const float* base, int c) {
        const float4* wp = reinterpret_cast<const float4*>(&wlds[c * 12]);
        const float4 wa = wp[0], wb = wp[1], wc = wp[2];
        const float wt[9] = {wa.x, wa.y, wa.z, wa.w, wb.x, wb.y, wb.z, wb.w, wc.x};
        if (active) {
#pragma unroll
            for (int k = 0; k < 6; ++k) {
                const float4 m = *reinterpret_cast<const float4*>(base + ro[k]);
                const float L = dpp_shr1(m.w);
                float       R = dpp_shl1(m.x);
                R = (s == 13) ? 0.f : R;
#pragma unroll
                for (int r = 0; r < 4; ++r) {
                    const int kh = k - r;
                    if (kh >= 0 && kh < 3) {
                        const float w0 = wt[kh * 3 + 0];
                        const float w1 = wt[kh * 3 + 1];
                        const float w2 = wt[kh * 3 + 2];
                        acc[r].x += w0 * L    + w1 * m.x + w2 * m.y;
                        acc[r].y += w0 * m.x  + w1 * m.y + w2 * m.z;
                        acc[r].z += w0 * m.y  + w1 * m.z + w2 * m.w;
                        acc[r].w += w0 * m.z  + w1 * m.w + w2 * R;
                    }
                }
            }
        }
    };

    // Prologue: stage channel 0 into buf[0].
    dma(0, &buf[0][0]);
    __syncthreads();

#pragma unroll 1
    for (int it = 0; it < 16; ++it) {
        const int c = 2 * it;
        // Phase A: DMA c+1 -> buf1 (hidden), compute c from buf0.
        dma(c + 1, &buf[1][0]);
        compute(&buf[0][0], c);
        __syncthreads();
        // Phase B: DMA c+2 -> buf0 (hidden), compute c+1 from buf1.
        if (it < 15) dma(c + 2, &buf[0][0]);
        compute(&buf[1][0], c + 1);
        __syncthreads();
    }

    if (active && s < 14) {
        float* ob = out + ((size_t)b * OC + o) * NPIX + (4 * g) * 56 + 4 * s;
#pragma unroll
        for (int r = 0; r < 4; ++r)
            *reinterpret_cast<float4*>(ob + r * 56) = acc[r];
    }
}

extern "C" void kernel_launch(void* const* d_in, const int* in_sizes, int n_in,
                              void* d_out, int out_size, void* d_ws, size_t ws_size,
                              hipStream_t stream) {
    const float* x    = (const float*)d_in[0];
    const float* wgt  = (const float*)d_in[1];
    const int*   conn = (const int*)d_in[2];
    float* out = (float*)d_out;

    dim3 grid(4 * OC);   // blockIdx = o*4 + b
    dim3 block(256);
    hipLaunchKernelGGL(sparse_conv_kernel, grid, block, 0, stream, x, wgt, conn, out);
}

// Round 9
// 116.301 us; speedup vs baseline: 1.0507x; 1.0507x over previous
//
#include <hip/hip_runtime.h>
#include <stdint.h>

#define NPIX 3136      // 56*56
#define OC 256
#define IC 256
#define CPF 32
#define BUFSZ 1856     // 7 DMA chunks * 256 + 64-float zero row
#define ZROW 1792      // zero "row" (serves out-of-window halo rows)
#define WLEN 1624      // stored window: 29 rows * 56
#define CLAMP 1620     // WLEN - 4 (tail clamp for last chunk)

typedef const __attribute__((address_space(1))) uint32_t* gptr_t;
typedef __attribute__((address_space(3))) uint32_t* lptr_t;

// lane s gets lane s-1's value within 16-lane DPP row; s%16==0 -> 0
__device__ __forceinline__ float dpp_shr1(float v) {
    return __int_as_float(__builtin_amdgcn_update_dpp(
        0, __float_as_int(v), 0x111, 0xF, 0xF, true));
}
// lane s gets lane s+1's value within 16-lane DPP row; s%16==15 -> 0
__device__ __forceinline__ float dpp_shl1(float v) {
    return __int_as_float(__builtin_amdgcn_update_dpp(
        0, __float_as_int(v), 0x101, 0xF, 0xF, true));
}

// One block per (b, o, half-plane): 28 output rows. 8 blocks/CU for latency
// slack (staggered barriers overlap). Plane window (29 rows) staged via
// global_load_lds DMA, double-buffered, 2-phase unrolled (compile-time LDS
// bases). Thread (g=t>>4, s=t&15) computes a 2x4 tile; weights/connections
// read as block-uniform global loads (scalar pipe).
__global__ __launch_bounds__(256, 8) void sparse_conv_kernel(
    const float* __restrict__ x, const float* __restrict__ weight,
    const int* __restrict__ connections, float* __restrict__ out)
{
    __shared__ __align__(16) float buf[2][BUFSZ];

    const int bid  = blockIdx.x;
    const int half = bid & 1;
    const int b    = (bid >> 1) & 3;   // bid%8 = (b,half): per-XCD L2 ~1.7MB
    const int o    = bid >> 3;
    const int t    = threadIdx.x;
    const int lane = t & 63;
    const int wv   = t >> 6;

    if (t < 64) { buf[0][ZROW + t] = 0.f; buf[1][ZROW + t] = 0.f; }

    const int r0 = half * 28;          // first output row of this block
    const int rs = half ? 27 : 0;      // first stored input row

    // DMA chunk offsets, hoisted. 7 chunks: wave w -> {w, w+4}, wave3 -> {3}.
    const int cnum = (wv == 3) ? 1 : 2;
    int goffs[2], coffs[2];
#pragma unroll
    for (int i = 0; i < 2; ++i) {
        const int chunk = wv + 4 * i;
        int go = chunk * 256 + lane * 4;
        goffs[i] = (go > CLAMP) ? CLAMP : go;   // duplicate-load tail, dest in pad
        coffs[i] = chunk * 256;
    }

    const float* xb   = x + (size_t)b * IC * NPIX + rs * 56;   // window base
    const int*   conn = connections + o * CPF;
    const float* wo   = weight + o * CPF * 9;

    const int s = t & 15;
    const int g = t >> 4;
    const bool active = (g < 14);

    // Hoisted LDS row offsets for the 4 input rows of this thread's 2x4 tile.
    int ro[4];
#pragma unroll
    for (int k = 0; k < 4; ++k) {
        const int rr = r0 + 2 * g - 1 + k;          // absolute input row
        const unsigned lr = (unsigned)(rr - rs);    // row within stored window
        ro[k] = ((lr <= 28u) ? (int)lr * 56 : ZROW) + 4 * s;
    }

    float4 acc[2];
    acc[0] = make_float4(0.f, 0.f, 0.f, 0.f);
    acc[1] = make_float4(0.f, 0.f, 0.f, 0.f);

    __syncthreads();   // zero rows visible

    auto dma = [&](int c, float* dst) {
        const float* plane = xb + (size_t)conn[c] * NPIX;   // conn: scalar load
        for (int i = 0; i < cnum; ++i)
            __builtin_amdgcn_global_load_lds((gptr_t)(plane + goffs[i]),
                                             (lptr_t)(dst + coffs[i]), 16, 0, 0);
    };

    auto compute = [&](const float* base, int c) {
        const float* wp = wo + c * 9;   // block-uniform -> s_load
        float wt[9];
#pragma unroll
        for (int k = 0; k < 9; ++k) wt[k] = wp[k];
        if (active) {
#pragma unroll
            for (int k = 0; k < 4; ++k) {
                const float4 m = *reinterpret_cast<const float4*>(base + ro[k]);
                const float L = dpp_shr1(m.w);
                float       R = dpp_shl1(m.x);
                R = (s == 13) ? 0.f : R;
#pragma unroll
                for (int r = 0; r < 2; ++r) {
                    const int kh = k - r;
                    if (kh >= 0 && kh < 3) {
                        const float w0 = wt[kh * 3 + 0];
                        const float w1 = wt[kh * 3 + 1];
                        const float w2 = wt[kh * 3 + 2];
                        acc[r].x += w0 * L    + w1 * m.x + w2 * m.y;
                        acc[r].y += w0 * m.x  + w1 * m.y + w2 * m.z;
                        acc[r].z += w0 * m.y  + w1 * m.z + w2 * m.w;
                        acc[r].w += w0 * m.z  + w1 * m.w + w2 * R;
                    }
                }
            }
        }
    };

    // Prologue: stage channel 0 into buf[0].
    dma(0, &buf[0][0]);
    __syncthreads();

#pragma unroll 1
    for (int it = 0; it < 16; ++it) {
        const int c = 2 * it;
        // Phase A: DMA c+1 -> buf1 (hidden under compute), compute c from buf0.
        dma(c + 1, &buf[1][0]);
        compute(&buf[0][0], c);
        __syncthreads();
        // Phase B: DMA c+2 -> buf0, compute c+1 from buf1.
        if (it < 15) dma(c + 2, &buf[0][0]);
        compute(&buf[1][0], c + 1);
        __syncthreads();
    }

    if (active && s < 14) {
        float* ob = out + ((size_t)b * OC + o) * NPIX + (r0 + 2 * g) * 56 + 4 * s;
        *reinterpret_cast<float4*>(ob)      = acc[0];
        *reinterpret_cast<float4*>(ob + 56) = acc[1];
    }
}

extern "C" void kernel_launch(void* const* d_in, const int* in_sizes, int n_in,
                              void* d_out, int out_size, void* d_ws, size_t ws_size,
                              hipStream_t stream) {
    const float* x    = (const float*)d_in[0];
    const float* wgt  = (const float*)d_in[1];
    const int*   conn = (const int*)d_in[2];
    float* out = (float*)d_out;

    dim3 grid(8 * OC);   // blockIdx = o*8 + b*2 + half
    dim3 block(256);
    hipLaunchKernelGGL(sparse_conv_kernel, grid, block, 0, stream, x, wgt, conn, out);
}

// Round 11
// 114.833 us; speedup vs baseline: 1.0642x; 1.0128x over previous
//
#include <hip/hip_runtime.h>
#include <stdint.h>

#define NPIX 3136      // 56*56
#define OC 256
#define IC 256
#define CPF 32

// lane s gets lane s-1's value within 16-lane DPP row; s%16==0 -> 0
__device__ __forceinline__ float dpp_shr1(float v) {
    return __int_as_float(__builtin_amdgcn_update_dpp(
        0, __float_as_int(v), 0x111, 0xF, 0xF, true));
}
// lane s gets lane s+1's value within 16-lane DPP row; s%16==15 -> 0
__device__ __forceinline__ float dpp_shl1(float v) {
    return __int_as_float(__builtin_amdgcn_update_dpp(
        0, __float_as_int(v), 0x101, 0xF, 0xF, true));
}

// One block per (b,o). NO LDS, NO barriers: x is L2-resident per XCD (~3 MB),
// so each thread reads its 6 input rows directly from global (saddr-form
// loads: uniform plane base in SGPRs + per-thread constant offset in VGPR).
// Thread (g=t>>4, s=t&15) computes a 4x4 output tile. Column halos via DPP;
// row halos via clamped address + per-k exec-mask (SALU only). Channels are
// software-pipelined 2 deep in registers (mA/mB).
__global__ __launch_bounds__(256, 4) void sparse_conv_kernel(
    const float* __restrict__ x, const float* __restrict__ weight,
    const int* __restrict__ connections, float* __restrict__ out)
{
    const int bid = blockIdx.x;
    const int b = bid & 3;        // consecutive bids -> different XCDs; each XCD
    const int o = bid >> 2;       // sees one b (~3 MB of x -> L2-resident)
    const int t = threadIdx.x;
    const int s = t & 15;
    const int g = t >> 4;
    const bool active = (g < 14);

    const float* xb   = x + (size_t)b * IC * NPIX;
    const int*   conn = connections + o * CPF;   // block-uniform -> s_load
    const float* wo   = weight + o * CPF * 9;    // block-uniform -> s_load

    // Per-thread row offsets (clamped to plane) + validity masks, hoisted.
    int off[6]; bool mk[6];
#pragma unroll
    for (int k = 0; k < 6; ++k) {
        const int rr = 4 * g - 1 + k;                       // input row
        const int rc = rr < 0 ? 0 : (rr > 55 ? 55 : rr);    // clamped (addr only)
        off[k] = rc * 56 + 4 * s;
        mk[k] = ((unsigned)rr < 56u) && active;
    }
    const bool redge = (s == 13);

    float4 acc[4];
#pragma unroll
    for (int r = 0; r < 4; ++r) acc[r] = make_float4(0.f, 0.f, 0.f, 0.f);

    auto loadrows = [&](int c, float4* m) {
        const float* plane = xb + (size_t)conn[c] * NPIX;   // SGPR base
#pragma unroll
        for (int k = 0; k < 6; ++k)
            m[k] = *reinterpret_cast<const float4*>(plane + off[k]);
    };

    auto compute = [&](const float4* m, int c) {
        const float* wp = wo + c * 9;
        float wt[9];
#pragma unroll
        for (int i = 0; i < 9; ++i) wt[i] = wp[i];          // s_load (uniform)
#pragma unroll
        for (int k = 0; k < 6; ++k) {
            if (mk[k]) {                                    // exec-mask, SALU only
                const float4 mm = m[k];
                const float L = dpp_shr1(mm.w);             // col 4s-1
                float       R = dpp_shl1(mm.x);             // col 4s+4
                R = redge ? 0.f : R;                        // right image edge
#pragma unroll
                for (int r = 0; r < 4; ++r) {
                    const int kh = k - r;
                    if (kh >= 0 && kh < 3) {
                        const float w0 = wt[kh * 3 + 0];
                        const float w1 = wt[kh * 3 + 1];
                        const float w2 = wt[kh * 3 + 2];
                        acc[r].x += w0 * L    + w1 * mm.x + w2 * mm.y;
                        acc[r].y += w0 * mm.x + w1 * mm.y + w2 * mm.z;
                        acc[r].z += w0 * mm.y + w1 * mm.z + w2 * mm.w;
                        acc[r].w += w0 * mm.z + w1 * mm.w + w2 * R;
                    }
                }
            }
        }
    };

    // 2-deep software pipeline over channels: load c+1 while computing c.
    float4 mA[6], mB[6];
    loadrows(0, mA);
#pragma unroll 1
    for (int it = 0; it < 16; ++it) {
        const int c = 2 * it;
        loadrows(c + 1, mB);
        compute(mA, c);
        if (it < 15) loadrows(c + 2, mA);
        compute(mB, c + 1);
    }

    if (active && s < 14) {
        float* ob = out + ((size_t)b * OC + o) * NPIX + (4 * g) * 56 + 4 * s;
#pragma unroll
        for (int r = 0; r < 4; ++r)
            *reinterpret_cast<float4*>(ob + r * 56) = acc[r];
    }
}

extern "C" void kernel_launch(void* const* d_in, const int* in_sizes, int n_in,
                              void* d_out, int out_size, void* d_ws, size_t ws_size,
                              hipStream_t stream) {
    const float* x    = (const float*)d_in[0];
    const float* wgt  = (const float*)d_in[1];
    const int*   conn = (const int*)d_in[2];
    float* out = (float*)d_out;

    dim3 grid(4 * OC);   // blockIdx = o*4 + b
    dim3 block(256);
    hipLaunchKernelGGL(sparse_conv_kernel, grid, block, 0, stream, x, wgt, conn, out);
}

// Round 12
// 101.055 us; speedup vs baseline: 1.2093x; 1.1363x over previous
//
#include <hip/hip_runtime.h>
#include <stdint.h>

#define NPIX 3136      // 56*56
#define OC 256
#define IC 256
#define CPF 32
#define XH_BYTES 6422528   // 3,211,264 halfs

typedef _Float16 h2_t __attribute__((ext_vector_type(2)));

__device__ __forceinline__ uint32_t pk16(float lo, float hi) {
    uint16_t l = __builtin_bit_cast(uint16_t, (_Float16)lo);
    uint16_t h = __builtin_bit_cast(uint16_t, (_Float16)hi);
    return (uint32_t)l | ((uint32_t)h << 16);
}
__device__ __forceinline__ float fdot2(uint32_t w, uint32_t xp, float acc) {
    return __builtin_amdgcn_fdot2(__builtin_bit_cast(h2_t, w),
                                  __builtin_bit_cast(h2_t, xp), acc, false);
}
// lane s gets lane s-1's value within 16-lane DPP row; s%16==0 -> 0
__device__ __forceinline__ uint32_t dpp_shr1(uint32_t v) {
    return (uint32_t)__builtin_amdgcn_update_dpp(0, (int)v, 0x111, 0xF, 0xF, true);
}
// lane s gets lane s+1's value within 16-lane DPP row; s%16==15 -> 0
__device__ __forceinline__ uint32_t dpp_shl1(uint32_t v) {
    return (uint32_t)__builtin_amdgcn_update_dpp(0, (int)v, 0x101, 0xF, 0xF, true);
}

// Pass 1: x fp32 -> fp16 (8 floats/thread; 1568*256*8 = 3,211,264 exactly).
__global__ __launch_bounds__(256) void cvt_x(const float* __restrict__ x,
                                             uint32_t* __restrict__ xh) {
    const int i = blockIdx.x * 256 + threadIdx.x;
    const float4 a = ((const float4*)x)[2 * i];
    const float4 b = ((const float4*)x)[2 * i + 1];
    uint4 o;
    o.x = pk16(a.x, a.y); o.y = pk16(a.z, a.w);
    o.z = pk16(b.x, b.y); o.w = pk16(b.z, b.w);
    ((uint4*)xh)[i] = o;
}

// Pass 2: weight fp32 -> channel-pair-packed fp16: wp[o][cc][kd] = (w[2cc],w[2cc+1]).
// 144 blocks * 256 = 36,864 = 256*16*9 exactly.
__global__ __launch_bounds__(256) void cvt_w(const float* __restrict__ w,
                                             uint32_t* __restrict__ wp) {
    const int i = blockIdx.x * 256 + threadIdx.x;
    const int o = i / 144, rem = i - o * 144;
    const int cc = rem / 9, kd = rem - cc * 9;
    const float w0 = w[(o * CPF + 2 * cc) * 9 + kd];
    const float w1 = w[(o * CPF + 2 * cc + 1) * 9 + kd];
    wp[i] = pk16(w0, w1);
}

// Main: one block per (b,o), no LDS/barriers (x fp16 is L2-resident per XCD).
// Thread (g=t>>4, s=t&15) computes a 4x4 fp32 tile. Channels processed in
// packed pairs via v_dot2_f32_f16 (2 MACs/inst, fp32 accumulate). Column
// halos via DPP; row halos via clamped addr + exec-mask. 2-deep pair pipeline.
__global__ __launch_bounds__(256, 4) void sparse_conv_kernel(
    const uint16_t* __restrict__ xh, const uint32_t* __restrict__ wp,
    const int* __restrict__ connections, float* __restrict__ out)
{
    const int bid = blockIdx.x;
    const int b = bid & 3;        // consecutive bids -> different XCDs
    const int o = bid >> 2;
    const int t = threadIdx.x;
    const int s = t & 15;
    const int g = t >> 4;
    const bool active = (g < 14);
    const bool redge = (s == 13);

    const int* conn = connections + o * CPF;        // block-uniform -> s_load
    const uint32_t* wo = wp + o * 144;              // 16 pairs * 9 taps

    // Row offsets (clamped rows AND cols -> never OOB) + validity masks.
    int off[6]; bool mk[6];
    const int col = (4 * s > 52) ? 52 : 4 * s;      // s>=14 lanes clamped
#pragma unroll
    for (int k = 0; k < 6; ++k) {
        const int rr = 4 * g - 1 + k;
        const int rc = rr < 0 ? 0 : (rr > 55 ? 55 : rr);
        off[k] = rc * 56 + col;
        mk[k] = ((unsigned)rr < 56u) && active;
    }

    float4 acc[4];
#pragma unroll
    for (int r = 0; r < 4; ++r) acc[r] = make_float4(0.f, 0.f, 0.f, 0.f);

    auto loadpair = [&](int cc, uint2* A, uint2* B) {
        const uint16_t* p0 = xh + ((size_t)b * IC + conn[2 * cc]) * NPIX;
        const uint16_t* p1 = xh + ((size_t)b * IC + conn[2 * cc + 1]) * NPIX;
#pragma unroll
        for (int k = 0; k < 6; ++k) {
            A[k] = *reinterpret_cast<const uint2*>(p0 + off[k]);
            B[k] = *reinterpret_cast<const uint2*>(p1 + off[k]);
        }
    };

    auto compute = [&](const uint2* A, const uint2* B, int cc) {
        uint32_t wt[9];
        const uint32_t* w9 = wo + cc * 9;
#pragma unroll
        for (int i = 0; i < 9; ++i) wt[i] = w9[i];  // uniform -> s_load
#pragma unroll
        for (int k = 0; k < 6; ++k) {
            if (mk[k]) {                            // exec-mask (SALU)
                // Interleave the two channels: I[j] = (chA[col j], chB[col j]).
                const uint32_t I0 = __builtin_amdgcn_perm(A[k].x, B[k].x, 0x01000504u);
                const uint32_t I1 = __builtin_amdgcn_perm(A[k].x, B[k].x, 0x03020706u);
                const uint32_t I2 = __builtin_amdgcn_perm(A[k].y, B[k].y, 0x01000504u);
                const uint32_t I3 = __builtin_amdgcn_perm(A[k].y, B[k].y, 0x03020706u);
                const uint32_t Lp = dpp_shr1(I3);   // col 4s-1 pair (0 at img edge)
                uint32_t       Rp = dpp_shl1(I0);   // col 4s+4 pair
                Rp = redge ? 0u : Rp;               // right image edge
#pragma unroll
                for (int r = 0; r < 4; ++r) {
                    const int kh = k - r;
                    if (kh >= 0 && kh < 3) {
                        const uint32_t w0 = wt[kh * 3 + 0];
                        const uint32_t w1 = wt[kh * 3 + 1];
                        const uint32_t w2 = wt[kh * 3 + 2];
                        acc[r].x = fdot2(w2, I1, fdot2(w1, I0, fdot2(w0, Lp, acc[r].x)));
                        acc[r].y = fdot2(w2, I2, fdot2(w1, I1, fdot2(w0, I0, acc[r].y)));
                        acc[r].z = fdot2(w2, I3, fdot2(w1, I2, fdot2(w0, I1, acc[r].z)));
                        acc[r].w = fdot2(w2, Rp, fdot2(w1, I3, fdot2(w0, I2, acc[r].w)));
                    }
                }
            }
        }
    };

    // 2-deep software pipeline over the 16 channel-pairs.
    uint2 A0[6], B0[6], A1[6], B1[6];
    loadpair(0, A0, B0);
#pragma unroll 1
    for (int it = 0; it < 8; ++it) {
        const int cc = 2 * it;
        loadpair(cc + 1, A1, B1);
        compute(A0, B0, cc);
        if (it < 7) loadpair(cc + 2, A0, B0);
        compute(A1, B1, cc + 1);
    }

    if (active && s < 14) {
        float* ob = out + ((size_t)b * OC + o) * NPIX + (4 * g) * 56 + 4 * s;
#pragma unroll
        for (int r = 0; r < 4; ++r)
            *reinterpret_cast<float4*>(ob + r * 56) = acc[r];
    }
}

extern "C" void kernel_launch(void* const* d_in, const int* in_sizes, int n_in,
                              void* d_out, int out_size, void* d_ws, size_t ws_size,
                              hipStream_t stream) {
    const float* x    = (const float*)d_in[0];
    const float* wgt  = (const float*)d_in[1];
    const int*   conn = (const int*)d_in[2];
    float* out = (float*)d_out;

    uint32_t* xh = (uint32_t*)d_ws;                          // 6,422,528 B
    uint32_t* wp = (uint32_t*)((char*)d_ws + XH_BYTES);      // +147,456 B

    hipLaunchKernelGGL(cvt_x, dim3(1568), dim3(256), 0, stream, x, xh);
    hipLaunchKernelGGL(cvt_w, dim3(144),  dim3(256), 0, stream, wgt, wp);
    hipLaunchKernelGGL(sparse_conv_kernel, dim3(4 * OC), dim3(256), 0, stream,
                       (const uint16_t*)xh, wp, conn, out);
}